// Round 5
// baseline (138.847 us; speedup 1.0000x reference)
//
#include <hip/hip_runtime.h>

#define HW 256
#define CH 64
#define NPIX (4 * HW * HW)              // 262144 pixels
#define ENC_BYTES ((size_t)NPIX * 24)   // 12 u16 per pixel (9 used)
#define DM_OFF ((size_t)8 << 20)        // dm region at ws+8MB
#define DM_BYTES ((size_t)NPIX * 48)    // 12 f32 per pixel (9 used)
#define WS_NEED (DM_OFF + DM_BYTES)

// ===================== Kernel A: address precompute (verified r2/r3) =====================
// One thread per (pixel, tap): enc = (y0<<8)|x0 u16. 36k waves -> latency-free.
__global__ __launch_bounds__(256, 8) void DeformA_kernel(
    const float* __restrict__ gt,     // [256,256]
    const float* __restrict__ off,    // [4,256,256,18]
    unsigned short* __restrict__ enc) // [NPIX][12]
{
    const unsigned g = blockIdx.x * 256u + threadIdx.x;   // < NPIX*9
    const unsigned p = g / 9u;                             // magic-mul
    const int tap = (int)(g - p * 9u);
    const int i = (int)((p >> 8) & 255u);
    const int j = (int)(p & 255u);
    const int ky = tap / 3, kx = tap - ky * 3;

    const float2 o2 = *(const float2*)(off + (size_t)g * 2);

    const int iy = i + ky - 1, ix = j + kx - 1;
    const bool interior = (iy >= 0) & (iy < HW) & (ix >= 0) & (ix < HW);
    const int yi = interior ? iy : 0;
    const int xi = interior ? ix : 0;
    const float p_mask = (yi >= 1 && xi >= 1) ? gt[(yi - 1) * HW + (xi - 1)] : 0.f;

    const float yf = (float)yi, xf = (float)xi;
    const float yof = fminf(fmaxf(floorf(yf + o2.x), 0.f), 257.f);
    const float xof = fminf(fmaxf(floorf(xf + o2.y), 0.f), 257.f);
    const int yo = (int)yof, xo = (int)xof;
    const float p_mask_off = (yo >= 1 && yo <= HW && xo >= 1 && xo <= HW)
                             ? gt[(yo - 1) * HW + (xo - 1)] : 0.f;
    const float diff = (p_mask != p_mask_off) ? 1.f : 0.f;
    const float y = fminf(fmaxf(yf + o2.x * diff, 0.f), 255.f);
    const float x = fminf(fmaxf(xf + o2.y * diff, 0.f), 255.f);
    const int y0 = (int)y, x0 = (int)x;   // in [0,255]; valid iff >=1

    enc[p * 12u + (unsigned)tap] = (unsigned short)((y0 << 8) | x0);
}

// ===================== Kernel D: tap dot-products (verified r4) =====================
// dm[p][k] = sum_c inp[p][c]*ker[k][c]. Fully coalesced streaming, BW-bound.
__global__ __launch_bounds__(256, 8) void DeformD_kernel(
    const float* __restrict__ inp,    // [NPIX][64]
    const float* __restrict__ ker,    // [9][64]
    float* __restrict__ dm)           // [NPIX][12]
{
    __shared__ float wlds[576];
    const int tid = threadIdx.x;
    if (tid < 144) ((float4*)wlds)[tid] = ((const float4*)ker)[tid];
    const float4* wq = (const float4*)wlds;

    const int lane = tid & 63;
    const int wave = tid >> 6;
    const int t = lane & 15;
    const int g = lane >> 4;

    const int p0 = blockIdx.x * 32 + (wave * 4 + g) * 2;   // pixels p0, p0+1

    const float4 v0 = *(const float4*)(inp + (size_t)p0 * 64 + t * 4);
    const float4 v1 = *(const float4*)(inp + (size_t)(p0 + 1) * 64 + t * 4);

    __syncthreads();

    float da[9], db[9];
    #pragma unroll
    for (int k = 0; k < 9; ++k) {
        const float4 w = wq[k * 16 + t];
        da[k] = v0.x * w.x + v0.y * w.y + v0.z * w.z + v0.w * w.w;
        db[k] = v1.x * w.x + v1.y * w.y + v1.z * w.z + v1.w * w.w;
    }
    #pragma unroll
    for (int k = 0; k < 9; ++k) {
        da[k] += __shfl_xor(da[k], 8);
        da[k] += __shfl_xor(da[k], 4);
        da[k] += __shfl_xor(da[k], 2);
        da[k] += __shfl_xor(da[k], 1);
        db[k] += __shfl_xor(db[k], 8);
        db[k] += __shfl_xor(db[k], 4);
        db[k] += __shfl_xor(db[k], 2);
        db[k] += __shfl_xor(db[k], 1);
    }
    float sa = da[8], sb = db[8];
    #pragma unroll
    for (int k = 7; k >= 0; --k) {
        sa = (t == k) ? da[k] : sa;
        sb = (t == k) ? db[k] : sb;
    }
    if (t < 9) {
        dm[(size_t)p0 * 12 + t] = sa;
        dm[(size_t)(p0 + 1) * 12 + t] = sb;
    }
}

// ===================== Kernel C2: gather precomputed dots =====================
// One thread per pixel. No gt, no off, no dependent address math: load 5
// words of enc, decode (pure VALU), 9 INDEPENDENT 4B gathers from the
// L2-resident dm table, sum, store. Chain ~450cy, ILP-9.
__global__ __launch_bounds__(256, 8) void DeformC2_kernel(
    const unsigned short* __restrict__ enc,  // [NPIX][12]
    const float* __restrict__ dm,            // [NPIX][12]
    const float* __restrict__ bias,
    float* __restrict__ out)                 // [NPIX]
{
    const int tid = threadIdx.x;
    const int bid = blockIdx.x;
    // XCD swizzle: contiguous 128-block chunk per XCD (1024 blocks)
    const int vb = (bid & 7) * 128 + (bid >> 3);
    const int p = vb * 256 + tid;
    const int b = p >> 16;
    const float* dmb = dm + (size_t)(b << 16) * 12;

    const uint2* e = (const uint2*)(enc + (size_t)p * 12u);
    const uint2 eA = e[0];                         // taps 0..3
    const uint2 eB = e[1];                         // taps 4..7
    const unsigned eC = *(const unsigned*)(e + 2); // tap 8

    unsigned en[9];
    en[0] = eA.x & 0xffffu; en[1] = eA.x >> 16;
    en[2] = eA.y & 0xffffu; en[3] = eA.y >> 16;
    en[4] = eB.x & 0xffffu; en[5] = eB.x >> 16;
    en[6] = eB.y & 0xffffu; en[7] = eB.y >> 16;
    en[8] = eC & 0xffffu;

    float v[9];
    int msk = 0;
    #pragma unroll
    for (int k = 0; k < 9; ++k) {
        const int yy = (int)(en[k] >> 8);
        const int xx = (int)(en[k] & 255u);
        const bool valid = (yy >= 1) & (xx >= 1);
        msk |= (int)valid << k;
        const int idx = valid ? ((yy - 1) * HW + (xx - 1)) : 0;
        v[k] = dmb[(size_t)idx * 12 + k];
    }
    float sum = 0.f;
    #pragma unroll
    for (int k = 0; k < 9; ++k)
        sum += ((msk >> k) & 1) ? v[k] : 0.f;

    out[p] = sum + bias[0];
}

// ===================== Fallback (round-0 verified kernel) =====================
__global__ __launch_bounds__(256, 6) void DeformFallback_kernel(
    const float* __restrict__ inp, const float* __restrict__ gt,
    const float* __restrict__ off, const float* __restrict__ ker,
    const float* __restrict__ bias, float* __restrict__ out)
{
    __shared__ float wlds[576];
    const int tid = threadIdx.x;
    if (tid < 144) ((float4*)wlds)[tid] = ((const float4*)ker)[tid];

    const int lane = tid & 63;
    const int wave = tid >> 6;
    const int q16  = lane & 48;
    const int t    = lane & 15;

    const int bid = blockIdx.x;
    const int vb  = (bid & 7) * 2048 + (bid >> 3);

    const int p = vb * 16 + wave * 4 + (q16 >> 4);
    const int b = p >> 16;
    const int i = (p >> 8) & 255;
    const int j = p & 255;
    const float* inb = inp + (long)b * (HW * HW * CH);

    int pack = 0;
    if (t < 9) {
        const int tap = t;
        const int ky = tap / 3, kx = tap - ky * 3;
        int iy = i + ky - 1, ix = j + kx - 1;
        bool interior = (iy >= 0) & (iy < HW) & (ix >= 0) & (ix < HW);
        int yi = interior ? iy : 0;
        int xi = interior ? ix : 0;
        float p_mask = (yi >= 1 && xi >= 1) ? gt[(yi - 1) * HW + (xi - 1)] : 0.f;
        float2 o2 = *(const float2*)(off + (long)p * 18 + 2 * tap);
        float yf = (float)yi, xf = (float)xi;
        float yof = fminf(fmaxf(floorf(yf + o2.x), 0.f), 257.f);
        float xof = fminf(fmaxf(floorf(xf + o2.y), 0.f), 257.f);
        int yo = (int)yof, xo = (int)xof;
        float p_mask_off = (yo >= 1 && yo <= HW && xo >= 1 && xo <= HW)
                           ? gt[(yo - 1) * HW + (xo - 1)] : 0.f;
        float diff = (p_mask != p_mask_off) ? 1.f : 0.f;
        float y = fminf(fmaxf(yf + o2.x * diff, 0.f), 255.f);
        float x = fminf(fmaxf(xf + o2.y * diff, 0.f), 255.f);
        int y0 = (int)y;
        int x0 = (int)x;
        bool valid = (y0 >= 1) & (x0 >= 1);
        int eoff = ((y0 - 1) * HW + (x0 - 1)) * CH;
        pack = valid ? eoff : -1;
    }

    int pk[9];
    #pragma unroll
    for (int k = 0; k < 9; ++k) pk[k] = __shfl(pack, q16 + k);

    float4 v[9];
    #pragma unroll
    for (int k = 0; k < 9; ++k) {
        int eo2 = pk[k] >= 0 ? pk[k] : 0;
        v[k] = *(const float4*)(inb + eo2 + t * 4);
    }

    __syncthreads();

    float acc = 0.f;
    #pragma unroll
    for (int k = 0; k < 9; ++k) {
        float s = pk[k] >= 0 ? 1.f : 0.f;
        float4 w = ((const float4*)wlds)[k * 16 + t];
        float d = v[k].x * w.x + v[k].y * w.y + v[k].z * w.z + v[k].w * w.w;
        acc = fmaf(s, d, acc);
    }

    acc += __shfl_xor(acc, 8);
    acc += __shfl_xor(acc, 4);
    acc += __shfl_xor(acc, 2);
    acc += __shfl_xor(acc, 1);
    if (t == 0) out[p] = acc + bias[0];
}

extern "C" void kernel_launch(void* const* d_in, const int* in_sizes, int n_in,
                              void* d_out, int out_size, void* d_ws, size_t ws_size,
                              hipStream_t stream) {
    const float* inp  = (const float*)d_in[0];
    const float* gt   = (const float*)d_in[1];
    const float* off  = (const float*)d_in[2];
    const float* ker  = (const float*)d_in[3];
    const float* bias = (const float*)d_in[4];
    float* out = (float*)d_out;

    if (d_ws != nullptr && ws_size >= WS_NEED) {
        unsigned short* enc = (unsigned short*)d_ws;
        float* dm = (float*)((char*)d_ws + DM_OFF);
        // A: 262144*9 / 256 = 9216 blocks ; D: 262144/32 = 8192 ; C2: 1024
        DeformA_kernel<<<9216, 256, 0, stream>>>(gt, off, enc);
        DeformD_kernel<<<8192, 256, 0, stream>>>(inp, ker, dm);
        DeformC2_kernel<<<1024, 256, 0, stream>>>(enc, dm, bias, out);
    } else {
        DeformFallback_kernel<<<16384, 256, 0, stream>>>(inp, gt, off, ker, bias, out);
    }
}

// Round 6
// 129.638 us; speedup vs baseline: 1.0710x; 1.0710x over previous
//
#include <hip/hip_runtime.h>

#define HW 256
#define CH 64
#define NPIX (4 * HW * HW)              // 262144 pixels
#define ENC_BYTES ((size_t)NPIX * 24)   // 12 u16 per pixel (9 used)
#define DM_OFF ((size_t)8 << 20)        // dm region at ws+8MB
#define DM_BYTES ((size_t)NPIX * 48)    // 12 f32 per pixel (9 used)
#define WS_NEED (DM_OFF + DM_BYTES)

// ===================== Kernel A: address precompute (verified r2/r3/r5) =====================
// One thread per (pixel, tap): enc = (y0<<8)|x0 u16. 36k waves -> latency-free.
__global__ __launch_bounds__(256, 8) void DeformA_kernel(
    const float* __restrict__ gt,     // [256,256]
    const float* __restrict__ off,    // [4,256,256,18]
    unsigned short* __restrict__ enc) // [NPIX][12]
{
    const unsigned g = blockIdx.x * 256u + threadIdx.x;   // < NPIX*9
    const unsigned p = g / 9u;                             // magic-mul
    const int tap = (int)(g - p * 9u);
    const int i = (int)((p >> 8) & 255u);
    const int j = (int)(p & 255u);
    const int ky = tap / 3, kx = tap - ky * 3;

    const float2 o2 = *(const float2*)(off + (size_t)g * 2);

    const int iy = i + ky - 1, ix = j + kx - 1;
    const bool interior = (iy >= 0) & (iy < HW) & (ix >= 0) & (ix < HW);
    const int yi = interior ? iy : 0;
    const int xi = interior ? ix : 0;
    const float p_mask = (yi >= 1 && xi >= 1) ? gt[(yi - 1) * HW + (xi - 1)] : 0.f;

    const float yf = (float)yi, xf = (float)xi;
    const float yof = fminf(fmaxf(floorf(yf + o2.x), 0.f), 257.f);
    const float xof = fminf(fmaxf(floorf(xf + o2.y), 0.f), 257.f);
    const int yo = (int)yof, xo = (int)xof;
    const float p_mask_off = (yo >= 1 && yo <= HW && xo >= 1 && xo <= HW)
                             ? gt[(yo - 1) * HW + (xo - 1)] : 0.f;
    const float diff = (p_mask != p_mask_off) ? 1.f : 0.f;
    const float y = fminf(fmaxf(yf + o2.x * diff, 0.f), 255.f);
    const float x = fminf(fmaxf(xf + o2.y * diff, 0.f), 255.f);
    const int y0 = (int)y, x0 = (int)x;   // in [0,255]; valid iff >=1

    enc[p * 12u + (unsigned)tap] = (unsigned short)((y0 << 8) | x0);
}

// ===================== Kernel D2: shuffle-free tap dot-products =====================
// dm[p][k] = sum_c inp[p][c]*ker[k][c].
// Round-5 lesson: the old D spent its time in 72 DS-pipe shuffle ops per
// thread (cross-lane reduce), ~35-40 us. D2 makes the dot LANE-LOCAL:
// one thread per pixel, acc[9] in VGPRs, 4 chunks x 16 channels. Each
// chunk load is exactly one 64B line per lane; ker addresses are
// wave-uniform + constant offsets -> scalar loads (SGPR operand FMAs).
// Zero shuffles, zero LDS. Floor = streaming 64MB read ~10us.
__global__ __launch_bounds__(256, 4) void DeformD2_kernel(
    const float* __restrict__ inp,    // [NPIX][64]
    const float* __restrict__ ker,    // [9][64]
    float* __restrict__ dm)           // [NPIX][12]
{
    const int p = blockIdx.x * 256 + threadIdx.x;
    const float* ip = inp + (size_t)p * 64;

    float acc[9];
    #pragma unroll
    for (int k = 0; k < 9; ++k) acc[k] = 0.f;

    #pragma unroll
    for (int c4 = 0; c4 < 4; ++c4) {          // 16 channels = one 64B line
        const float4 a = *(const float4*)(ip + c4 * 16 + 0);
        const float4 b = *(const float4*)(ip + c4 * 16 + 4);
        const float4 c = *(const float4*)(ip + c4 * 16 + 8);
        const float4 d = *(const float4*)(ip + c4 * 16 + 12);
        #pragma unroll
        for (int k = 0; k < 9; ++k) {
            const float* kr = ker + k * 64 + c4 * 16;   // uniform -> s_load
            const float4 wa = *(const float4*)(kr + 0);
            const float4 wb = *(const float4*)(kr + 4);
            const float4 wc = *(const float4*)(kr + 8);
            const float4 wd = *(const float4*)(kr + 12);
            acc[k] = fmaf(a.x, wa.x, acc[k]); acc[k] = fmaf(a.y, wa.y, acc[k]);
            acc[k] = fmaf(a.z, wa.z, acc[k]); acc[k] = fmaf(a.w, wa.w, acc[k]);
            acc[k] = fmaf(b.x, wb.x, acc[k]); acc[k] = fmaf(b.y, wb.y, acc[k]);
            acc[k] = fmaf(b.z, wb.z, acc[k]); acc[k] = fmaf(b.w, wb.w, acc[k]);
            acc[k] = fmaf(c.x, wc.x, acc[k]); acc[k] = fmaf(c.y, wc.y, acc[k]);
            acc[k] = fmaf(c.z, wc.z, acc[k]); acc[k] = fmaf(c.w, wc.w, acc[k]);
            acc[k] = fmaf(d.x, wd.x, acc[k]); acc[k] = fmaf(d.y, wd.y, acc[k]);
            acc[k] = fmaf(d.z, wd.z, acc[k]); acc[k] = fmaf(d.w, wd.w, acc[k]);
        }
    }

    float4* o = (float4*)(dm + (size_t)p * 12);
    const float4 s0 = {acc[0], acc[1], acc[2], acc[3]};
    const float4 s1 = {acc[4], acc[5], acc[6], acc[7]};
    const float4 s2 = {acc[8], 0.f, 0.f, 0.f};
    o[0] = s0; o[1] = s1; o[2] = s2;
}

// ===================== Kernel C2: gather precomputed dots (r5) =====================
__global__ __launch_bounds__(256, 8) void DeformC2_kernel(
    const unsigned short* __restrict__ enc,  // [NPIX][12]
    const float* __restrict__ dm,            // [NPIX][12]
    const float* __restrict__ bias,
    float* __restrict__ out)                 // [NPIX]
{
    const int tid = threadIdx.x;
    const int bid = blockIdx.x;
    const int vb = (bid & 7) * 128 + (bid >> 3);   // XCD swizzle, 1024 blocks
    const int p = vb * 256 + tid;
    const int b = p >> 16;
    const float* dmb = dm + (size_t)(b << 16) * 12;

    const uint2* e = (const uint2*)(enc + (size_t)p * 12u);
    const uint2 eA = e[0];                         // taps 0..3
    const uint2 eB = e[1];                         // taps 4..7
    const unsigned eC = *(const unsigned*)(e + 2); // tap 8

    unsigned en[9];
    en[0] = eA.x & 0xffffu; en[1] = eA.x >> 16;
    en[2] = eA.y & 0xffffu; en[3] = eA.y >> 16;
    en[4] = eB.x & 0xffffu; en[5] = eB.x >> 16;
    en[6] = eB.y & 0xffffu; en[7] = eB.y >> 16;
    en[8] = eC & 0xffffu;

    float v[9];
    int msk = 0;
    #pragma unroll
    for (int k = 0; k < 9; ++k) {
        const int yy = (int)(en[k] >> 8);
        const int xx = (int)(en[k] & 255u);
        const bool valid = (yy >= 1) & (xx >= 1);
        msk |= (int)valid << k;
        const int idx = valid ? ((yy - 1) * HW + (xx - 1)) : 0;
        v[k] = dmb[(size_t)idx * 12 + k];
    }
    float sum = 0.f;
    #pragma unroll
    for (int k = 0; k < 9; ++k)
        sum += ((msk >> k) & 1) ? v[k] : 0.f;

    out[p] = sum + bias[0];
}

// ===================== Fallback (round-0 verified kernel) =====================
__global__ __launch_bounds__(256, 6) void DeformFallback_kernel(
    const float* __restrict__ inp, const float* __restrict__ gt,
    const float* __restrict__ off, const float* __restrict__ ker,
    const float* __restrict__ bias, float* __restrict__ out)
{
    __shared__ float wlds[576];
    const int tid = threadIdx.x;
    if (tid < 144) ((float4*)wlds)[tid] = ((const float4*)ker)[tid];

    const int lane = tid & 63;
    const int wave = tid >> 6;
    const int q16  = lane & 48;
    const int t    = lane & 15;

    const int bid = blockIdx.x;
    const int vb  = (bid & 7) * 2048 + (bid >> 3);

    const int p = vb * 16 + wave * 4 + (q16 >> 4);
    const int b = p >> 16;
    const int i = (p >> 8) & 255;
    const int j = p & 255;
    const float* inb = inp + (long)b * (HW * HW * CH);

    int pack = 0;
    if (t < 9) {
        const int tap = t;
        const int ky = tap / 3, kx = tap - ky * 3;
        int iy = i + ky - 1, ix = j + kx - 1;
        bool interior = (iy >= 0) & (iy < HW) & (ix >= 0) & (ix < HW);
        int yi = interior ? iy : 0;
        int xi = interior ? ix : 0;
        float p_mask = (yi >= 1 && xi >= 1) ? gt[(yi - 1) * HW + (xi - 1)] : 0.f;
        float2 o2 = *(const float2*)(off + (long)p * 18 + 2 * tap);
        float yf = (float)yi, xf = (float)xi;
        float yof = fminf(fmaxf(floorf(yf + o2.x), 0.f), 257.f);
        float xof = fminf(fmaxf(floorf(xf + o2.y), 0.f), 257.f);
        int yo = (int)yof, xo = (int)xof;
        float p_mask_off = (yo >= 1 && yo <= HW && xo >= 1 && xo <= HW)
                           ? gt[(yo - 1) * HW + (xo - 1)] : 0.f;
        float diff = (p_mask != p_mask_off) ? 1.f : 0.f;
        float y = fminf(fmaxf(yf + o2.x * diff, 0.f), 255.f);
        float x = fminf(fmaxf(xf + o2.y * diff, 0.f), 255.f);
        int y0 = (int)y;
        int x0 = (int)x;
        bool valid = (y0 >= 1) & (x0 >= 1);
        int eoff = ((y0 - 1) * HW + (x0 - 1)) * CH;
        pack = valid ? eoff : -1;
    }

    int pk[9];
    #pragma unroll
    for (int k = 0; k < 9; ++k) pk[k] = __shfl(pack, q16 + k);

    float4 v[9];
    #pragma unroll
    for (int k = 0; k < 9; ++k) {
        int eo2 = pk[k] >= 0 ? pk[k] : 0;
        v[k] = *(const float4*)(inb + eo2 + t * 4);
    }

    __syncthreads();

    float acc = 0.f;
    #pragma unroll
    for (int k = 0; k < 9; ++k) {
        float s = pk[k] >= 0 ? 1.f : 0.f;
        float4 w = ((const float4*)wlds)[k * 16 + t];
        float d = v[k].x * w.x + v[k].y * w.y + v[k].z * w.z + v[k].w * w.w;
        acc = fmaf(s, d, acc);
    }

    acc += __shfl_xor(acc, 8);
    acc += __shfl_xor(acc, 4);
    acc += __shfl_xor(acc, 2);
    acc += __shfl_xor(acc, 1);
    if (t == 0) out[p] = acc + bias[0];
}

extern "C" void kernel_launch(void* const* d_in, const int* in_sizes, int n_in,
                              void* d_out, int out_size, void* d_ws, size_t ws_size,
                              hipStream_t stream) {
    const float* inp  = (const float*)d_in[0];
    const float* gt   = (const float*)d_in[1];
    const float* off  = (const float*)d_in[2];
    const float* ker  = (const float*)d_in[3];
    const float* bias = (const float*)d_in[4];
    float* out = (float*)d_out;

    if (d_ws != nullptr && ws_size >= WS_NEED) {
        unsigned short* enc = (unsigned short*)d_ws;
        float* dm = (float*)((char*)d_ws + DM_OFF);
        // A: 262144*9 / 256 = 9216 blocks ; D2: 262144/256 = 1024 ; C2: 1024
        DeformA_kernel<<<9216, 256, 0, stream>>>(gt, off, enc);
        DeformD2_kernel<<<1024, 256, 0, stream>>>(inp, ker, dm);
        DeformC2_kernel<<<1024, 256, 0, stream>>>(enc, dm, bias, out);
    } else {
        DeformFallback_kernel<<<16384, 256, 0, stream>>>(inp, gt, off, ker, bias, out);
    }
}

// Round 8
// 124.078 us; speedup vs baseline: 1.1190x; 1.0448x over previous
//
#include <hip/hip_runtime.h>

#define HW 256
#define CH 64
#define NPIX (4 * HW * HW)              // 262144 pixels
#define ENC_BYTES ((size_t)NPIX * 24)   // 12 u16 per pixel (9 used)
#define DM_OFF ((size_t)8 << 20)        // dm region at ws+8MB
#define DM_BYTES ((size_t)NPIX * 48)    // 12 f32 per pixel (9 used)
#define WS_NEED (DM_OFF + DM_BYTES)

// ===================== Kernel A: address precompute (verified r2/r3/r5/r6) =====================
// One thread per (pixel, tap): enc = (y0<<8)|x0 u16. 36k waves -> latency-free.
__global__ __launch_bounds__(256, 8) void DeformA_kernel(
    const float* __restrict__ gt,     // [256,256]
    const float* __restrict__ off,    // [4,256,256,18]
    unsigned short* __restrict__ enc) // [NPIX][12]
{
    const unsigned g = blockIdx.x * 256u + threadIdx.x;   // < NPIX*9
    const unsigned p = g / 9u;                             // magic-mul
    const int tap = (int)(g - p * 9u);
    const int i = (int)((p >> 8) & 255u);
    const int j = (int)(p & 255u);
    const int ky = tap / 3, kx = tap - ky * 3;

    const float2 o2 = *(const float2*)(off + (size_t)g * 2);

    const int iy = i + ky - 1, ix = j + kx - 1;
    const bool interior = (iy >= 0) & (iy < HW) & (ix >= 0) & (ix < HW);
    const int yi = interior ? iy : 0;
    const int xi = interior ? ix : 0;
    const float p_mask = (yi >= 1 && xi >= 1) ? gt[(yi - 1) * HW + (xi - 1)] : 0.f;

    const float yf = (float)yi, xf = (float)xi;
    const float yof = fminf(fmaxf(floorf(yf + o2.x), 0.f), 257.f);
    const float xof = fminf(fmaxf(floorf(xf + o2.y), 0.f), 257.f);
    const int yo = (int)yof, xo = (int)xof;
    const float p_mask_off = (yo >= 1 && yo <= HW && xo >= 1 && xo <= HW)
                             ? gt[(yo - 1) * HW + (xo - 1)] : 0.f;
    const float diff = (p_mask != p_mask_off) ? 1.f : 0.f;
    const float y = fminf(fmaxf(yf + o2.x * diff, 0.f), 255.f);
    const float x = fminf(fmaxf(xf + o2.y * diff, 0.f), 255.f);
    const int y0 = (int)y, x0 = (int)x;   // in [0,255]; valid iff >=1

    enc[p * 12u + (unsigned)tap] = (unsigned short)((y0 << 8) | x0);
}

// ---- DPP rotate-add: x + rotate_right_within_16_row(x, N). VALU pipe, no DS.
// CTRL must be an immediate: template parameter (Sema checks before inlining).
template <int CTRL>
__device__ __forceinline__ float dpp_ror_add(float x) {
    int xi = __builtin_bit_cast(int, x);
    int yi = __builtin_amdgcn_update_dpp(0, xi, CTRL, 0xF, 0xF, false);
    return x + __builtin_bit_cast(float, yi);
}
#define ROR1 0x121
#define ROR2 0x122
#define ROR4 0x124
#define ROR8 0x128

// ===================== Kernel D3: tap dot-products, DPP reduce =====================
// dm[p][k] = sum_c inp[p][c]*ker[k][c].
// Round-6 lesson: D2's lane-per-pixel layout made every VMEM instr touch
// 64 cache lines (L1-pipe bound, ~34us). D1's 16-lane/px layout had ideal
// coalescing but burned ~26us in 72 ds_swizzle (DS pipe, serialized per
// CU). D3 = D1's exact verified structure with the reduce moved to the
// VALU: DPP row_ror butterfly (8/4/2/1) leaves the 16-lane sum in every
// lane; store path identical to D1.
__global__ __launch_bounds__(256, 8) void DeformD3_kernel(
    const float* __restrict__ inp,    // [NPIX][64]
    const float* __restrict__ ker,    // [9][64]
    float* __restrict__ dm)           // [NPIX][12]
{
    __shared__ float wlds[576];
    const int tid = threadIdx.x;
    if (tid < 144) ((float4*)wlds)[tid] = ((const float4*)ker)[tid];
    const float4* wq = (const float4*)wlds;

    const int lane = tid & 63;
    const int wave = tid >> 6;
    const int t = lane & 15;
    const int g = lane >> 4;

    const int p0 = blockIdx.x * 32 + (wave * 4 + g) * 2;   // pixels p0, p0+1

    const float4 v0 = *(const float4*)(inp + (size_t)p0 * 64 + t * 4);
    const float4 v1 = *(const float4*)(inp + (size_t)(p0 + 1) * 64 + t * 4);

    __syncthreads();                  // weights staged

    float da[9], db[9];
    #pragma unroll
    for (int k = 0; k < 9; ++k) {
        const float4 w = wq[k * 16 + t];
        da[k] = v0.x * w.x + v0.y * w.y + v0.z * w.z + v0.w * w.w;
        db[k] = v1.x * w.x + v1.y * w.y + v1.z * w.z + v1.w * w.w;
    }
    // 16-lane rotate-butterfly per tap (VALU/DPP; every lane ends with total)
    #pragma unroll
    for (int k = 0; k < 9; ++k) {
        da[k] = dpp_ror_add<ROR8>(da[k]);
        da[k] = dpp_ror_add<ROR4>(da[k]);
        da[k] = dpp_ror_add<ROR2>(da[k]);
        da[k] = dpp_ror_add<ROR1>(da[k]);
        db[k] = dpp_ror_add<ROR8>(db[k]);
        db[k] = dpp_ror_add<ROR4>(db[k]);
        db[k] = dpp_ror_add<ROR2>(db[k]);
        db[k] = dpp_ror_add<ROR1>(db[k]);
    }
    // lane t stores tap t (static select chain, no runtime indexing)
    float sa = da[8], sb = db[8];
    #pragma unroll
    for (int k = 7; k >= 0; --k) {
        sa = (t == k) ? da[k] : sa;
        sb = (t == k) ? db[k] : sb;
    }
    if (t < 9) {
        dm[(size_t)p0 * 12 + t] = sa;
        dm[(size_t)(p0 + 1) * 12 + t] = sb;
    }
}

// ===================== Kernel C2: gather precomputed dots (verified r5/r6) =====================
__global__ __launch_bounds__(256, 8) void DeformC2_kernel(
    const unsigned short* __restrict__ enc,  // [NPIX][12]
    const float* __restrict__ dm,            // [NPIX][12]
    const float* __restrict__ bias,
    float* __restrict__ out)                 // [NPIX]
{
    const int tid = threadIdx.x;
    const int bid = blockIdx.x;
    const int vb = (bid & 7) * 128 + (bid >> 3);   // XCD swizzle, 1024 blocks
    const int p = vb * 256 + tid;
    const int b = p >> 16;
    const float* dmb = dm + (size_t)(b << 16) * 12;

    const uint2* e = (const uint2*)(enc + (size_t)p * 12u);
    const uint2 eA = e[0];                         // taps 0..3
    const uint2 eB = e[1];                         // taps 4..7
    const unsigned eC = *(const unsigned*)(e + 2); // tap 8

    unsigned en[9];
    en[0] = eA.x & 0xffffu; en[1] = eA.x >> 16;
    en[2] = eA.y & 0xffffu; en[3] = eA.y >> 16;
    en[4] = eB.x & 0xffffu; en[5] = eB.x >> 16;
    en[6] = eB.y & 0xffffu; en[7] = eB.y >> 16;
    en[8] = eC & 0xffffu;

    float v[9];
    int msk = 0;
    #pragma unroll
    for (int k = 0; k < 9; ++k) {
        const int yy = (int)(en[k] >> 8);
        const int xx = (int)(en[k] & 255u);
        const bool valid = (yy >= 1) & (xx >= 1);
        msk |= (int)valid << k;
        const int idx = valid ? ((yy - 1) * HW + (xx - 1)) : 0;
        v[k] = dmb[(size_t)idx * 12 + k];
    }
    float sum = 0.f;
    #pragma unroll
    for (int k = 0; k < 9; ++k)
        sum += ((msk >> k) & 1) ? v[k] : 0.f;

    out[p] = sum + bias[0];
}

// ===================== Fallback (round-0 verified kernel) =====================
__global__ __launch_bounds__(256, 6) void DeformFallback_kernel(
    const float* __restrict__ inp, const float* __restrict__ gt,
    const float* __restrict__ off, const float* __restrict__ ker,
    const float* __restrict__ bias, float* __restrict__ out)
{
    __shared__ float wlds[576];
    const int tid = threadIdx.x;
    if (tid < 144) ((float4*)wlds)[tid] = ((const float4*)ker)[tid];

    const int lane = tid & 63;
    const int wave = tid >> 6;
    const int q16  = lane & 48;
    const int t    = lane & 15;

    const int bid = blockIdx.x;
    const int vb  = (bid & 7) * 2048 + (bid >> 3);

    const int p = vb * 16 + wave * 4 + (q16 >> 4);
    const int b = p >> 16;
    const int i = (p >> 8) & 255;
    const int j = p & 255;
    const float* inb = inp + (long)b * (HW * HW * CH);

    int pack = 0;
    if (t < 9) {
        const int tap = t;
        const int ky = tap / 3, kx = tap - ky * 3;
        int iy = i + ky - 1, ix = j + kx - 1;
        bool interior = (iy >= 0) & (iy < HW) & (ix >= 0) & (ix < HW);
        int yi = interior ? iy : 0;
        int xi = interior ? ix : 0;
        float p_mask = (yi >= 1 && xi >= 1) ? gt[(yi - 1) * HW + (xi - 1)] : 0.f;
        float2 o2 = *(const float2*)(off + (long)p * 18 + 2 * tap);
        float yf = (float)yi, xf = (float)xi;
        float yof = fminf(fmaxf(floorf(yf + o2.x), 0.f), 257.f);
        float xof = fminf(fmaxf(floorf(xf + o2.y), 0.f), 257.f);
        int yo = (int)yof, xo = (int)xof;
        float p_mask_off = (yo >= 1 && yo <= HW && xo >= 1 && xo <= HW)
                           ? gt[(yo - 1) * HW + (xo - 1)] : 0.f;
        float diff = (p_mask != p_mask_off) ? 1.f : 0.f;
        float y = fminf(fmaxf(yf + o2.x * diff, 0.f), 255.f);
        float x = fminf(fmaxf(xf + o2.y * diff, 0.f), 255.f);
        int y0 = (int)y;
        int x0 = (int)x;
        bool valid = (y0 >= 1) & (x0 >= 1);
        int eoff = ((y0 - 1) * HW + (x0 - 1)) * CH;
        pack = valid ? eoff : -1;
    }

    int pk[9];
    #pragma unroll
    for (int k = 0; k < 9; ++k) pk[k] = __shfl(pack, q16 + k);

    float4 v[9];
    #pragma unroll
    for (int k = 0; k < 9; ++k) {
        int eo2 = pk[k] >= 0 ? pk[k] : 0;
        v[k] = *(const float4*)(inb + eo2 + t * 4);
    }

    __syncthreads();

    float acc = 0.f;
    #pragma unroll
    for (int k = 0; k < 9; ++k) {
        float s = pk[k] >= 0 ? 1.f : 0.f;
        float4 w = ((const float4*)wlds)[k * 16 + t];
        float d = v[k].x * w.x + v[k].y * w.y + v[k].z * w.z + v[k].w * w.w;
        acc = fmaf(s, d, acc);
    }

    acc += __shfl_xor(acc, 8);
    acc += __shfl_xor(acc, 4);
    acc += __shfl_xor(acc, 2);
    acc += __shfl_xor(acc, 1);
    if (t == 0) out[p] = acc + bias[0];
}

extern "C" void kernel_launch(void* const* d_in, const int* in_sizes, int n_in,
                              void* d_out, int out_size, void* d_ws, size_t ws_size,
                              hipStream_t stream) {
    const float* inp  = (const float*)d_in[0];
    const float* gt   = (const float*)d_in[1];
    const float* off  = (const float*)d_in[2];
    const float* ker  = (const float*)d_in[3];
    const float* bias = (const float*)d_in[4];
    float* out = (float*)d_out;

    if (d_ws != nullptr && ws_size >= WS_NEED) {
        unsigned short* enc = (unsigned short*)d_ws;
        float* dm = (float*)((char*)d_ws + DM_OFF);
        // A: 262144*9 / 256 = 9216 blocks ; D3: 262144/32 = 8192 ; C2: 1024
        DeformA_kernel<<<9216, 256, 0, stream>>>(gt, off, enc);
        DeformD3_kernel<<<8192, 256, 0, stream>>>(inp, ker, dm);
        DeformC2_kernel<<<1024, 256, 0, stream>>>(enc, dm, bias, out);
    } else {
        DeformFallback_kernel<<<16384, 256, 0, stream>>>(inp, gt, off, ker, bias, out);
    }
}